// Round 2
// baseline (402.976 us; speedup 1.0000x reference)
//
#include <hip/hip_runtime.h>
#include <math.h>

// CapsuleLayer dynamic routing, fully fused recompute formulation.
// Shapes: x[B=128, J=2048, I=8], W[J, K=32, I, D=16] -> v[B, K, D]
//
// b_t = (sum_{tau<t} v_tau) . u_hat  (linearity, b0 = 0), so we only keep
// vsum[b,k,d] (256 KB) and recompute u_hat per sweep from x and W.
//
// R1 -> R2: sweeps were latency-bound (occ 20%, VALUBusy 27%, grid=1 block/CU).
//   BW 8->4: grid 256->512 blocks (2/CU), launch_bounds(512,4) => VGPR<=128,
//   4 waves/SIMD. Softmax max-subtraction removed (|logit| <~ 12 << 88).

constexpr int Bn = 128;
constexpr int Jn = 2048;
constexpr int In = 8;
constexpr int Kn = 32;
constexpr int Dn = 16;
constexpr int KD = Kn * Dn;          // 512
constexpr int CELLS = Bn * KD;       // 65536

constexpr int JT    = 16;            // j per workgroup
constexpr int NJB   = Jn / JT;       // 128 j-blocks (= #partials per cell)
constexpr int WAVES = 8;
constexpr int BLOCK = WAVES * 64;    // 512 threads
constexpr int BW    = 4;             // batches per wave (s-acc in regs)
constexpr int BGW   = WAVES * BW;    // 32 batches per workgroup
constexpr int NBB   = Bn / BGW;      // 4 b-blocks
constexpr int GRID_SWEEP = NBB * NJB; // 512 workgroups = 2 blocks/CU

// PHASE: 0 = uniform c (softmax of zeros = 1/K), 1/2 = softmax(vsum . u_hat)
// ATOMIC=false: write per-(j-block) partials (exactly-once, non-atomic)
// ATOMIC=true : atomicAdd into a single s buffer (small-ws fallback)
template <int PHASE, bool ATOMIC>
__global__ __launch_bounds__(BLOCK, 4)
void sweep_kernel(const float* __restrict__ x, const float* __restrict__ W,
                  const float* __restrict__ vsum, float* __restrict__ sout)
{
    const int jb    = blockIdx.x % NJB;
    const int b0    = (blockIdx.x / NJB) * BGW;
    const int wave  = threadIdx.x >> 6;
    const int lane  = threadIdx.x & 63;
    const int k     = lane >> 1;            // lane pair per output capsule
    const int d0    = (lane & 1) * 8;       // half of D per lane
    const int bbase = b0 + wave * BW;

    float sacc[BW][8];
#pragma unroll
    for (int b = 0; b < BW; ++b)
#pragma unroll
        for (int r = 0; r < 8; ++r) sacc[b][r] = 0.f;

    const int j0 = jb * JT;
    for (int jj = 0; jj < JT; ++jj) {
        const int j = j0 + jj;

        // W[j, k, i, d0..d0+7] fragment -> 64 VGPRs, reused for BW batches
        float Wr[In][8];
        const float* wp = W + ((size_t)j * Kn + k) * (In * Dn) + d0;
#pragma unroll
        for (int i = 0; i < In; ++i) {
            const float4 a  = *reinterpret_cast<const float4*>(wp + i * Dn);
            const float4 b4 = *reinterpret_cast<const float4*>(wp + i * Dn + 4);
            Wr[i][0] = a.x;  Wr[i][1] = a.y;  Wr[i][2] = a.z;  Wr[i][3] = a.w;
            Wr[i][4] = b4.x; Wr[i][5] = b4.y; Wr[i][6] = b4.z; Wr[i][7] = b4.w;
        }

#pragma unroll
        for (int bb = 0; bb < BW; ++bb) {
            const int b = bbase + bb;

            // x[b, j, 0..7] : wave-uniform broadcast load
            const float* xp = x + ((size_t)b * Jn + j) * In;
            const float4 xa = *reinterpret_cast<const float4*>(xp);
            const float4 xb = *reinterpret_cast<const float4*>(xp + 4);
            const float xv[8] = {xa.x, xa.y, xa.z, xa.w, xb.x, xb.y, xb.z, xb.w};

            // u_hat[b, k, j, d0+r] = sum_i x[b,j,i] * W[j,k,i,d0+r]
            float uh[8];
#pragma unroll
            for (int r = 0; r < 8; ++r) {
                float acc = xv[0] * Wr[0][r];
#pragma unroll
                for (int i = 1; i < In; ++i) acc = fmaf(xv[i], Wr[i][r], acc);
                uh[r] = acc;
            }

            if (PHASE == 0) {
                // c is uniform 1/K; fold the 1/32 into the squash kernel
#pragma unroll
                for (int r = 0; r < 8; ++r) sacc[bb][r] += uh[r];
            } else {
                // logit[k] = vsum[b,k,:] . u_hat[b,k,j,:]
                const float* vp = vsum + ((size_t)b * Kn + k) * Dn + d0;
                const float4 va = *reinterpret_cast<const float4*>(vp);
                const float4 vb = *reinterpret_cast<const float4*>(vp + 4);
                float p = va.x * uh[0];
                p = fmaf(va.y, uh[1], p);
                p = fmaf(va.z, uh[2], p);
                p = fmaf(va.w, uh[3], p);
                p = fmaf(vb.x, uh[4], p);
                p = fmaf(vb.y, uh[5], p);
                p = fmaf(vb.z, uh[6], p);
                p = fmaf(vb.w, uh[7], p);
                p += __shfl_xor(p, 1);   // reduce the two d-halves -> full dot

                // softmax over k WITHOUT max subtraction: |p| <= |vsum||uhat|
                // <~ 3*4 = 12 << 88 (fp32 exp range), so exp never overflows.
                // masks 2..32 mix only same-parity lanes -> each k counted once.
                const float e = __expf(p);
                float ssum = e;
#pragma unroll
                for (int mk = 2; mk <= 32; mk <<= 1)
                    ssum += __shfl_xor(ssum, mk);
#if __has_builtin(__builtin_amdgcn_rcpf)
                const float c = e * __builtin_amdgcn_rcpf(ssum);
#else
                const float c = e / ssum;
#endif
#pragma unroll
                for (int r = 0; r < 8; ++r)
                    sacc[bb][r] = fmaf(c, uh[r], sacc[bb][r]);
            }
        }
    }

    // epilogue: dump per-wave s partials
#pragma unroll
    for (int bb = 0; bb < BW; ++bb) {
        const int b = bbase + bb;
        const size_t cell = ((size_t)b * Kn + k) * Dn + d0;
        if (ATOMIC) {
#pragma unroll
            for (int r = 0; r < 8; ++r)
                atomicAdd(sout + cell + r, sacc[bb][r]);
        } else {
            const float4 f0 = make_float4(sacc[bb][0], sacc[bb][1], sacc[bb][2], sacc[bb][3]);
            const float4 f1 = make_float4(sacc[bb][4], sacc[bb][5], sacc[bb][6], sacc[bb][7]);
            float* dst = sout + (size_t)jb * CELLS + cell;
            *reinterpret_cast<float4*>(dst)     = f0;
            *reinterpret_cast<float4*>(dst + 4) = f1;
        }
    }
}

// Reduce partials (or consume the atomic buffer), apply squash, update vsum,
// and on the final phase write v to d_out. 16384 threads, 4 cells each.
template <int PHASE, bool ATOMIC>
__global__ __launch_bounds__(256)
void squash_kernel(float* __restrict__ sbuf, float* __restrict__ vsum,
                   float* __restrict__ outv)
{
    const int t = blockIdx.x * blockDim.x + threadIdx.x;   // 0..16383
    const size_t c4 = (size_t)t * 4;

    float4 s;
    if (ATOMIC) {
        s = *reinterpret_cast<const float4*>(sbuf + c4);
        // re-zero for the next sweep in this launch
        *reinterpret_cast<float4*>(sbuf + c4) = make_float4(0.f, 0.f, 0.f, 0.f);
    } else {
        s = make_float4(0.f, 0.f, 0.f, 0.f);
#pragma unroll 4
        for (int p = 0; p < NJB; ++p) {
            const float4 v = *reinterpret_cast<const float4*>(sbuf + (size_t)p * CELLS + c4);
            s.x += v.x; s.y += v.y; s.z += v.z; s.w += v.w;
        }
    }

    if (PHASE == 0) {  // uniform c = 1/K was folded out of the sweep
        const float sc = 1.f / 32.f;
        s.x *= sc; s.y *= sc; s.z *= sc; s.w *= sc;
    }

    // squash over D=16 -> 4 consecutive threads per (b,k)
    float s2 = s.x * s.x + s.y * s.y + s.z * s.z + s.w * s.w;
    s2 += __shfl_xor(s2, 1);
    s2 += __shfl_xor(s2, 2);
    const float scale = s2 / ((1.f + s2) * sqrtf(s2 + 1e-7f));
    const float4 v4 = make_float4(s.x * scale, s.y * scale, s.z * scale, s.w * scale);

    if (PHASE == 2) {
        *reinterpret_cast<float4*>(outv + c4) = v4;
    } else if (PHASE == 0) {
        *reinterpret_cast<float4*>(vsum + c4) = v4;           // vsum = v0
    } else {
        float4 o = *reinterpret_cast<const float4*>(vsum + c4);
        o.x += v4.x; o.y += v4.y; o.z += v4.z; o.w += v4.w;   // vsum += v1
        *reinterpret_cast<float4*>(vsum + c4) = o;
    }
}

extern "C" void kernel_launch(void* const* d_in, const int* in_sizes, int n_in,
                              void* d_out, int out_size, void* d_ws, size_t ws_size,
                              hipStream_t stream)
{
    const float* x = (const float*)d_in[0];
    const float* W = (const float*)d_in[1];
    float* out = (float*)d_out;

    const size_t partial_bytes = (size_t)NJB * CELLS * sizeof(float);  // 32 MB
    const size_t vsum_bytes    = (size_t)CELLS * sizeof(float);        // 256 KB

    const dim3 gs(GRID_SWEEP), bs(BLOCK);
    const dim3 gq(CELLS / 4 / 256), bq(256);

    if (ws_size >= partial_bytes + vsum_bytes) {
        float* partial = (float*)d_ws;
        float* vsum    = (float*)((char*)d_ws + partial_bytes);
        sweep_kernel<0, false><<<gs, bs, 0, stream>>>(x, W, vsum, partial);
        squash_kernel<0, false><<<gq, bq, 0, stream>>>(partial, vsum, out);
        sweep_kernel<1, false><<<gs, bs, 0, stream>>>(x, W, vsum, partial);
        squash_kernel<1, false><<<gq, bq, 0, stream>>>(partial, vsum, out);
        sweep_kernel<2, false><<<gs, bs, 0, stream>>>(x, W, vsum, partial);
        squash_kernel<2, false><<<gq, bq, 0, stream>>>(partial, vsum, out);
    } else {
        // small-workspace fallback: single 256 KB accumulator + atomics
        float* sbuf = (float*)d_ws;
        float* vsum = (float*)((char*)d_ws + vsum_bytes);
        hipMemsetAsync(sbuf, 0, vsum_bytes, stream);
        sweep_kernel<0, true><<<gs, bs, 0, stream>>>(x, W, vsum, sbuf);
        squash_kernel<0, true><<<gq, bq, 0, stream>>>(sbuf, vsum, out);
        sweep_kernel<1, true><<<gs, bs, 0, stream>>>(x, W, vsum, sbuf);
        squash_kernel<1, true><<<gq, bq, 0, stream>>>(sbuf, vsum, out);
        sweep_kernel<2, true><<<gs, bs, 0, stream>>>(x, W, vsum, sbuf);
        squash_kernel<2, true><<<gq, bq, 0, stream>>>(sbuf, vsum, out);
    }
}

// Round 4
// 395.025 us; speedup vs baseline: 1.0201x; 1.0201x over previous
//
#include <hip/hip_runtime.h>
#include <math.h>

// CapsuleLayer dynamic routing, fused recompute formulation.
// x[B=128, J=2048, I=8], W[J, K=32, I, D=16] -> v[B, K, D]
// b_t = (sum_{tau<t} v_tau) . u_hat, so keep only vsum[b,k,d] and recompute
// u_hat each sweep.
//
// R2 -> R3: sweeps were L1 line-throughput bound (strided per-thread W loads
// touched ~12K lines/CU/j vs 3.5K VALU cycles; VALUBusy 22%). Now:
//  - W[j] slice (16 KB contiguous) staged to LDS via global_load_lds width-16,
//    double-buffered, XOR-swizzled (L ^ ((k&7)<<4)) on source+read (rule #21).
//  - vsum hoisted to registers (j-invariant).
//  - BLOCK=256 (4 waves), BW=4, grid=1024, launch_bounds(256,3).
// R3 -> R4: R3 never ran (GPU acquisition timeout). Resubmitting unchanged.

constexpr int Bn = 128;
constexpr int Jn = 2048;
constexpr int In = 8;
constexpr int Kn = 32;
constexpr int Dn = 16;
constexpr int KD = Kn * Dn;          // 512
constexpr int CELLS = Bn * KD;       // 65536

constexpr int JT    = 16;            // j per workgroup
constexpr int NJB   = Jn / JT;       // 128 j-blocks
constexpr int WAVES = 4;
constexpr int BLOCK = WAVES * 64;    // 256 threads
constexpr int BW    = 4;             // batches per wave
constexpr int BGW   = WAVES * BW;    // 16 batches per workgroup
constexpr int NBB   = Bn / BGW;      // 8 b-blocks
constexpr int GRID_SWEEP = NBB * NJB; // 1024 workgroups
constexpr int WSLICE = Kn * In * Dn; // 4096 floats = 16 KB per j
constexpr int WBYTES = WSLICE * 4;

// Stage W[j] (16 KB contiguous) into LDS. Linear LDS dest (HW: wave-uniform
// base + lane*16); the bank-swizzle is applied by permuting the GLOBAL source
// address with the same involution the reader uses (guide rule #21).
__device__ __forceinline__ void stage_w(const float* __restrict__ Wj,
                                        float* dstf, int wave, int lane)
{
#pragma unroll
    for (int c = 0; c < 4; ++c) {
        const int M = c * 4096 + wave * 1024 + lane * 16;   // LDS byte offset
        const int G = M ^ (((M >> 9) & 7) << 4);            // swizzled source
        __builtin_amdgcn_global_load_lds(
            (const __attribute__((address_space(1))) void*)((const char*)Wj + G),
            (__attribute__((address_space(3))) void*)((char*)dstf + c * 4096 + wave * 1024),
            16, 0, 0);
    }
}

// PHASE: 0 = uniform c (softmax of zeros), 1/2 = softmax(vsum . u_hat)
template <int PHASE, bool ATOMIC>
__global__ __launch_bounds__(BLOCK, 3)
void sweep_kernel(const float* __restrict__ x, const float* __restrict__ W,
                  const float* __restrict__ vsum, float* __restrict__ sout)
{
    __shared__ float wlds[2 * WSLICE];   // 32 KB double buffer

    const int jb    = blockIdx.x % NJB;
    const int b0    = (blockIdx.x / NJB) * BGW;
    const int wave  = threadIdx.x >> 6;
    const int lane  = threadIdx.x & 63;
    const int kk    = lane >> 1;             // output capsule
    const int dh    = lane & 1;              // d-half (8 floats)
    const int bbase = b0 + wave * BW;
    const int kmask = (kk & 7) << 4;         // read-side swizzle
    const int Lbase = kk * 512 + dh * 32;    // byte offset in 16 KB slice (bit4==0)

    // vsum[b, kk, d0..d0+7] is j-invariant: hoist to registers.
    float vs[BW][8];
    if (PHASE != 0) {
#pragma unroll
        for (int bb = 0; bb < BW; ++bb) {
            const float* vp = vsum + ((size_t)(bbase + bb) * Kn + kk) * Dn + dh * 8;
            const float4 a  = *reinterpret_cast<const float4*>(vp);
            const float4 b4 = *reinterpret_cast<const float4*>(vp + 4);
            vs[bb][0] = a.x;  vs[bb][1] = a.y;  vs[bb][2] = a.z;  vs[bb][3] = a.w;
            vs[bb][4] = b4.x; vs[bb][5] = b4.y; vs[bb][6] = b4.z; vs[bb][7] = b4.w;
        }
    }

    float sacc[BW][8];
#pragma unroll
    for (int bb = 0; bb < BW; ++bb)
#pragma unroll
        for (int r = 0; r < 8; ++r) sacc[bb][r] = 0.f;

    const int j0 = jb * JT;
    stage_w(W + (size_t)j0 * WSLICE, wlds, wave, lane);   // prologue
    __syncthreads();                                      // drains vmcnt

#pragma unroll 2
    for (int jj = 0; jj < JT; ++jj) {
        const int j   = j0 + jj;
        const int buf = jj & 1;

        if (jj + 1 < JT)   // prefetch next slice; lands under this j's compute
            stage_w(W + (size_t)(j + 1) * WSLICE, wlds + (buf ^ 1) * WSLICE, wave, lane);

        // x[b, j, 0..7]: wave-uniform broadcast loads
        float xv[BW][8];
#pragma unroll
        for (int bb = 0; bb < BW; ++bb) {
            const float* xp = x + ((size_t)(bbase + bb) * Jn + j) * In;
            const float4 xa = *reinterpret_cast<const float4*>(xp);
            const float4 xb = *reinterpret_cast<const float4*>(xp + 4);
            xv[bb][0] = xa.x; xv[bb][1] = xa.y; xv[bb][2] = xa.z; xv[bb][3] = xa.w;
            xv[bb][4] = xb.x; xv[bb][5] = xb.y; xv[bb][6] = xb.z; xv[bb][7] = xb.w;
        }

        // u_hat from LDS-staged W (i-streamed: 8 live W regs)
        float uh[BW][8];
#pragma unroll
        for (int bb = 0; bb < BW; ++bb)
#pragma unroll
            for (int r = 0; r < 8; ++r) uh[bb][r] = 0.f;

        const char* wb = (const char*)wlds + buf * WBYTES;
#pragma unroll
        for (int i = 0; i < In; ++i) {
            const int a0 = (Lbase + i * 64) ^ kmask;
            const float4 wa = *reinterpret_cast<const float4*>(wb + a0);
            const float4 wc = *reinterpret_cast<const float4*>(wb + (a0 ^ 16));
            const float w8[8] = {wa.x, wa.y, wa.z, wa.w, wc.x, wc.y, wc.z, wc.w};
#pragma unroll
            for (int bb = 0; bb < BW; ++bb)
#pragma unroll
                for (int r = 0; r < 8; ++r)
                    uh[bb][r] = fmaf(xv[bb][i], w8[r], uh[bb][r]);
        }

        if (PHASE == 0) {
#pragma unroll
            for (int bb = 0; bb < BW; ++bb)
#pragma unroll
                for (int r = 0; r < 8; ++r) sacc[bb][r] += uh[bb][r];
        } else {
#pragma unroll
            for (int bb = 0; bb < BW; ++bb) {
                float p = vs[bb][0] * uh[bb][0];
#pragma unroll
                for (int r = 1; r < 8; ++r) p = fmaf(vs[bb][r], uh[bb][r], p);
                p += __shfl_xor(p, 1);   // combine d-halves -> full dot

                // no max-subtraction: |p| <= ~12 << 88, exp can't overflow
                const float e = __expf(p);
                float ss = e;
#pragma unroll
                for (int mk = 2; mk <= 32; mk <<= 1)
                    ss += __shfl_xor(ss, mk);
#if __has_builtin(__builtin_amdgcn_rcpf)
                const float c = e * __builtin_amdgcn_rcpf(ss);
#else
                const float c = e / ss;
#endif
#pragma unroll
                for (int r = 0; r < 8; ++r)
                    sacc[bb][r] = fmaf(c, uh[bb][r], sacc[bb][r]);
            }
        }
        __syncthreads();   // buf reads done + next-buf stage landed
    }

    // epilogue: dump per-wave s partials
#pragma unroll
    for (int bb = 0; bb < BW; ++bb) {
        const int b = bbase + bb;
        const size_t cell = ((size_t)b * Kn + kk) * Dn + dh * 8;
        if (ATOMIC) {
#pragma unroll
            for (int r = 0; r < 8; ++r)
                atomicAdd(sout + cell + r, sacc[bb][r]);
        } else {
            const float4 f0 = make_float4(sacc[bb][0], sacc[bb][1], sacc[bb][2], sacc[bb][3]);
            const float4 f1 = make_float4(sacc[bb][4], sacc[bb][5], sacc[bb][6], sacc[bb][7]);
            float* dst = sout + (size_t)jb * CELLS + cell;
            *reinterpret_cast<float4*>(dst)     = f0;
            *reinterpret_cast<float4*>(dst + 4) = f1;
        }
    }
}

// Reduce partials, squash, update vsum; final phase writes v to d_out.
template <int PHASE, bool ATOMIC>
__global__ __launch_bounds__(256)
void squash_kernel(float* __restrict__ sbuf, float* __restrict__ vsum,
                   float* __restrict__ outv)
{
    const int t = blockIdx.x * blockDim.x + threadIdx.x;   // 0..16383
    const size_t c4 = (size_t)t * 4;

    float4 s;
    if (ATOMIC) {
        s = *reinterpret_cast<const float4*>(sbuf + c4);
        *reinterpret_cast<float4*>(sbuf + c4) = make_float4(0.f, 0.f, 0.f, 0.f);
    } else {
        s = make_float4(0.f, 0.f, 0.f, 0.f);
#pragma unroll 4
        for (int p = 0; p < NJB; ++p) {
            const float4 v = *reinterpret_cast<const float4*>(sbuf + (size_t)p * CELLS + c4);
            s.x += v.x; s.y += v.y; s.z += v.z; s.w += v.w;
        }
    }

    if (PHASE == 0) {  // uniform c = 1/K folded out of the sweep
        const float sc = 1.f / 32.f;
        s.x *= sc; s.y *= sc; s.z *= sc; s.w *= sc;
    }

    float s2 = s.x * s.x + s.y * s.y + s.z * s.z + s.w * s.w;
    s2 += __shfl_xor(s2, 1);
    s2 += __shfl_xor(s2, 2);
    const float scale = s2 / ((1.f + s2) * sqrtf(s2 + 1e-7f));
    const float4 v4 = make_float4(s.x * scale, s.y * scale, s.z * scale, s.w * scale);

    if (PHASE == 2) {
        *reinterpret_cast<float4*>(outv + c4) = v4;
    } else if (PHASE == 0) {
        *reinterpret_cast<float4*>(vsum + c4) = v4;
    } else {
        float4 o = *reinterpret_cast<const float4*>(vsum + c4);
        o.x += v4.x; o.y += v4.y; o.z += v4.z; o.w += v4.w;
        *reinterpret_cast<float4*>(vsum + c4) = o;
    }
}

extern "C" void kernel_launch(void* const* d_in, const int* in_sizes, int n_in,
                              void* d_out, int out_size, void* d_ws, size_t ws_size,
                              hipStream_t stream)
{
    const float* x = (const float*)d_in[0];
    const float* W = (const float*)d_in[1];
    float* out = (float*)d_out;

    const size_t partial_bytes = (size_t)NJB * CELLS * sizeof(float);  // 32 MB
    const size_t vsum_bytes    = (size_t)CELLS * sizeof(float);        // 256 KB

    const dim3 gs(GRID_SWEEP), bs(BLOCK);
    const dim3 gq(CELLS / 4 / 256), bq(256);

    if (ws_size >= partial_bytes + vsum_bytes) {
        float* partial = (float*)d_ws;
        float* vsum    = (float*)((char*)d_ws + partial_bytes);
        sweep_kernel<0, false><<<gs, bs, 0, stream>>>(x, W, vsum, partial);
        squash_kernel<0, false><<<gq, bq, 0, stream>>>(partial, vsum, out);
        sweep_kernel<1, false><<<gs, bs, 0, stream>>>(x, W, vsum, partial);
        squash_kernel<1, false><<<gq, bq, 0, stream>>>(partial, vsum, out);
        sweep_kernel<2, false><<<gs, bs, 0, stream>>>(x, W, vsum, partial);
        squash_kernel<2, false><<<gq, bq, 0, stream>>>(partial, vsum, out);
    } else {
        float* sbuf = (float*)d_ws;
        float* vsum = (float*)((char*)d_ws + vsum_bytes);
        hipMemsetAsync(sbuf, 0, vsum_bytes, stream);
        sweep_kernel<0, true><<<gs, bs, 0, stream>>>(x, W, vsum, sbuf);
        squash_kernel<0, true><<<gq, bq, 0, stream>>>(sbuf, vsum, out);
        sweep_kernel<1, true><<<gs, bs, 0, stream>>>(x, W, vsum, sbuf);
        squash_kernel<1, true><<<gq, bq, 0, stream>>>(sbuf, vsum, out);
        sweep_kernel<2, true><<<gs, bs, 0, stream>>>(x, W, vsum, sbuf);
        squash_kernel<2, true><<<gq, bq, 0, stream>>>(sbuf, vsum, out);
    }
}

// Round 5
// 284.353 us; speedup vs baseline: 1.4172x; 1.3892x over previous
//
#include <hip/hip_runtime.h>
#include <math.h>

// CapsuleLayer dynamic routing, fused recompute formulation.
// x[B=128, J=2048, I=8], W[J, K=32, I, D=16] -> v[B, K, D]
// b_t = (sum_{tau<t} v_tau) . u_hat, so keep only vsum[b,k,d] and recompute
// u_hat each sweep.
//
// R4 -> R5: diagnosis = register spills. VGPR_Count=84 but PHASE1/2 live set
// >=128 floats (sacc+vs+uh+xv) -- my launch_bounds(...,3) forced the allocator
// under the live set; WRITE_SIZE 112MB vs 32MB partials (~300B/thread) is the
// scratch traffic; PHASE0 (no softmax) ran identically -> not softmax.
// Fix: BW 4->2 (live ~95), launch_bounds(256,4) (cap 128, no spill),
// JT 16->32 (partials 32->16MB, grid 1024 = exactly 4 wg/CU, 16 waves/CU).

constexpr int Bn = 128;
constexpr int Jn = 2048;
constexpr int In = 8;
constexpr int Kn = 32;
constexpr int Dn = 16;
constexpr int KD = Kn * Dn;          // 512
constexpr int CELLS = Bn * KD;       // 65536

constexpr int JT    = 32;            // j per workgroup
constexpr int NJB   = Jn / JT;       // 64 j-blocks
constexpr int WAVES = 4;
constexpr int BLOCK = WAVES * 64;    // 256 threads
constexpr int BW    = 2;             // batches per wave (small live set!)
constexpr int BGW   = WAVES * BW;    // 8 batches per workgroup
constexpr int NBB   = Bn / BGW;      // 16 b-blocks
constexpr int GRID_SWEEP = NBB * NJB; // 1024 workgroups = 4/CU, one round
constexpr int WSLICE = Kn * In * Dn; // 4096 floats = 16 KB per j
constexpr int WBYTES = WSLICE * 4;

// Stage W[j] (16 KB contiguous) into LDS. Linear LDS dest (HW: wave-uniform
// base + lane*16); bank-swizzle applied by permuting the GLOBAL source address
// with the same involution the reader uses (guide rule #21). XOR touches bits
// 4-6 only; bits 9-11 (its key) are invariant -> involution verified, and
// R4 passed with absmax 2e-3.
__device__ __forceinline__ void stage_w(const float* __restrict__ Wj,
                                        float* dstf, int tid)
{
#pragma unroll
    for (int c = 0; c < 4; ++c) {
        const int M = c * 4096 + tid * 16;        // LDS byte offset
        const int G = M ^ (((M >> 9) & 7) << 4);  // swizzled source
        __builtin_amdgcn_global_load_lds(
            (const __attribute__((address_space(1))) void*)((const char*)Wj + G),
            (__attribute__((address_space(3))) void*)((char*)dstf + M),
            16, 0, 0);
    }
}

// PHASE: 0 = uniform c (softmax of zeros), 1/2 = softmax(vsum . u_hat)
template <int PHASE, bool ATOMIC>
__global__ __launch_bounds__(BLOCK, 4)
void sweep_kernel(const float* __restrict__ x, const float* __restrict__ W,
                  const float* __restrict__ vsum, float* __restrict__ sout)
{
    __shared__ float wlds[2 * WSLICE];   // 32 KB double buffer

    const int jb    = blockIdx.x % NJB;
    const int b0    = (blockIdx.x / NJB) * BGW;
    const int tid   = threadIdx.x;
    const int wave  = tid >> 6;
    const int lane  = tid & 63;
    const int kk    = lane >> 1;             // output capsule
    const int dh    = lane & 1;              // d-half (8 floats)
    const int bbase = b0 + wave * BW;
    const int kmask = (kk & 7) << 4;         // read-side swizzle
    const int Lbase = kk * 512 + dh * 32;    // byte offset in 16 KB slice

    // vsum[b, kk, d0..d0+7] is j-invariant: hoist to registers.
    float vs[BW][8];
    if (PHASE != 0) {
#pragma unroll
        for (int bb = 0; bb < BW; ++bb) {
            const float* vp = vsum + ((size_t)(bbase + bb) * Kn + kk) * Dn + dh * 8;
            const float4 a  = *reinterpret_cast<const float4*>(vp);
            const float4 b4 = *reinterpret_cast<const float4*>(vp + 4);
            vs[bb][0] = a.x;  vs[bb][1] = a.y;  vs[bb][2] = a.z;  vs[bb][3] = a.w;
            vs[bb][4] = b4.x; vs[bb][5] = b4.y; vs[bb][6] = b4.z; vs[bb][7] = b4.w;
        }
    }

    float sacc[BW][8];
#pragma unroll
    for (int bb = 0; bb < BW; ++bb)
#pragma unroll
        for (int r = 0; r < 8; ++r) sacc[bb][r] = 0.f;

    const int j0 = jb * JT;
    stage_w(W + (size_t)j0 * WSLICE, wlds, tid);   // prologue
    __syncthreads();                               // drains vmcnt

#pragma unroll 2
    for (int jj = 0; jj < JT; ++jj) {
        const int j   = j0 + jj;
        const int buf = jj & 1;

        if (jj + 1 < JT)   // prefetch next slice; lands under this j's compute
            stage_w(W + (size_t)(j + 1) * WSLICE, wlds + (buf ^ 1) * WSLICE, tid);

        // x[b, j, 0..7]: wave-uniform broadcast loads
        float xv[BW][8];
#pragma unroll
        for (int bb = 0; bb < BW; ++bb) {
            const float* xp = x + ((size_t)(bbase + bb) * Jn + j) * In;
            const float4 xa = *reinterpret_cast<const float4*>(xp);
            const float4 xb = *reinterpret_cast<const float4*>(xp + 4);
            xv[bb][0] = xa.x; xv[bb][1] = xa.y; xv[bb][2] = xa.z; xv[bb][3] = xa.w;
            xv[bb][4] = xb.x; xv[bb][5] = xb.y; xv[bb][6] = xb.z; xv[bb][7] = xb.w;
        }

        // u_hat from LDS-staged W (i-streamed: 8 live W regs)
        float uh[BW][8];
#pragma unroll
        for (int bb = 0; bb < BW; ++bb)
#pragma unroll
            for (int r = 0; r < 8; ++r) uh[bb][r] = 0.f;

        const char* wb = (const char*)wlds + buf * WBYTES;
#pragma unroll
        for (int i = 0; i < In; ++i) {
            const int a0 = (Lbase + i * 64) ^ kmask;
            const float4 wa = *reinterpret_cast<const float4*>(wb + a0);
            const float4 wc = *reinterpret_cast<const float4*>(wb + (a0 ^ 16));
            const float w8[8] = {wa.x, wa.y, wa.z, wa.w, wc.x, wc.y, wc.z, wc.w};
#pragma unroll
            for (int bb = 0; bb < BW; ++bb)
#pragma unroll
                for (int r = 0; r < 8; ++r)
                    uh[bb][r] = fmaf(xv[bb][i], w8[r], uh[bb][r]);
        }

        if (PHASE == 0) {
#pragma unroll
            for (int bb = 0; bb < BW; ++bb)
#pragma unroll
                for (int r = 0; r < 8; ++r) sacc[bb][r] += uh[bb][r];
        } else {
#pragma unroll
            for (int bb = 0; bb < BW; ++bb) {
                float p = vs[bb][0] * uh[bb][0];
#pragma unroll
                for (int r = 1; r < 8; ++r) p = fmaf(vs[bb][r], uh[bb][r], p);
                p += __shfl_xor(p, 1);   // combine d-halves -> full dot

                // no max-subtraction: |p| <= ~12 << 88, exp can't overflow
                const float e = __expf(p);
                float ss = e;
#pragma unroll
                for (int mk = 2; mk <= 32; mk <<= 1)
                    ss += __shfl_xor(ss, mk);
#if __has_builtin(__builtin_amdgcn_rcpf)
                const float c = e * __builtin_amdgcn_rcpf(ss);
#else
                const float c = e / ss;
#endif
#pragma unroll
                for (int r = 0; r < 8; ++r)
                    sacc[bb][r] = fmaf(c, uh[bb][r], sacc[bb][r]);
            }
        }
        __syncthreads();   // buf reads done + next-buf stage landed
    }

    // epilogue: dump per-wave s partials
#pragma unroll
    for (int bb = 0; bb < BW; ++bb) {
        const int b = bbase + bb;
        const size_t cell = ((size_t)b * Kn + kk) * Dn + dh * 8;
        if (ATOMIC) {
#pragma unroll
            for (int r = 0; r < 8; ++r)
                atomicAdd(sout + cell + r, sacc[bb][r]);
        } else {
            const float4 f0 = make_float4(sacc[bb][0], sacc[bb][1], sacc[bb][2], sacc[bb][3]);
            const float4 f1 = make_float4(sacc[bb][4], sacc[bb][5], sacc[bb][6], sacc[bb][7]);
            float* dst = sout + (size_t)jb * CELLS + cell;
            *reinterpret_cast<float4*>(dst)     = f0;
            *reinterpret_cast<float4*>(dst + 4) = f1;
        }
    }
}

// Reduce partials, squash, update vsum; final phase writes v to d_out.
template <int PHASE, bool ATOMIC>
__global__ __launch_bounds__(256)
void squash_kernel(float* __restrict__ sbuf, float* __restrict__ vsum,
                   float* __restrict__ outv)
{
    const int t = blockIdx.x * blockDim.x + threadIdx.x;   // 0..16383
    const size_t c4 = (size_t)t * 4;

    float4 s;
    if (ATOMIC) {
        s = *reinterpret_cast<const float4*>(sbuf + c4);
        *reinterpret_cast<float4*>(sbuf + c4) = make_float4(0.f, 0.f, 0.f, 0.f);
    } else {
        s = make_float4(0.f, 0.f, 0.f, 0.f);
#pragma unroll 4
        for (int p = 0; p < NJB; ++p) {
            const float4 v = *reinterpret_cast<const float4*>(sbuf + (size_t)p * CELLS + c4);
            s.x += v.x; s.y += v.y; s.z += v.z; s.w += v.w;
        }
    }

    if (PHASE == 0) {  // uniform c = 1/K folded out of the sweep
        const float sc = 1.f / 32.f;
        s.x *= sc; s.y *= sc; s.z *= sc; s.w *= sc;
    }

    float s2 = s.x * s.x + s.y * s.y + s.z * s.z + s.w * s.w;
    s2 += __shfl_xor(s2, 1);
    s2 += __shfl_xor(s2, 2);
    const float scale = s2 / ((1.f + s2) * sqrtf(s2 + 1e-7f));
    const float4 v4 = make_float4(s.x * scale, s.y * scale, s.z * scale, s.w * scale);

    if (PHASE == 2) {
        *reinterpret_cast<float4*>(outv + c4) = v4;
    } else if (PHASE == 0) {
        *reinterpret_cast<float4*>(vsum + c4) = v4;
    } else {
        float4 o = *reinterpret_cast<const float4*>(vsum + c4);
        o.x += v4.x; o.y += v4.y; o.z += v4.z; o.w += v4.w;
        *reinterpret_cast<float4*>(vsum + c4) = o;
    }
}

extern "C" void kernel_launch(void* const* d_in, const int* in_sizes, int n_in,
                              void* d_out, int out_size, void* d_ws, size_t ws_size,
                              hipStream_t stream)
{
    const float* x = (const float*)d_in[0];
    const float* W = (const float*)d_in[1];
    float* out = (float*)d_out;

    const size_t partial_bytes = (size_t)NJB * CELLS * sizeof(float);  // 16 MB
    const size_t vsum_bytes    = (size_t)CELLS * sizeof(float);        // 256 KB

    const dim3 gs(GRID_SWEEP), bs(BLOCK);
    const dim3 gq(CELLS / 4 / 256), bq(256);

    if (ws_size >= partial_bytes + vsum_bytes) {
        float* partial = (float*)d_ws;
        float* vsum    = (float*)((char*)d_ws + partial_bytes);
        sweep_kernel<0, false><<<gs, bs, 0, stream>>>(x, W, vsum, partial);
        squash_kernel<0, false><<<gq, bq, 0, stream>>>(partial, vsum, out);
        sweep_kernel<1, false><<<gs, bs, 0, stream>>>(x, W, vsum, partial);
        squash_kernel<1, false><<<gq, bq, 0, stream>>>(partial, vsum, out);
        sweep_kernel<2, false><<<gs, bs, 0, stream>>>(x, W, vsum, partial);
        squash_kernel<2, false><<<gq, bq, 0, stream>>>(partial, vsum, out);
    } else {
        float* sbuf = (float*)d_ws;
        float* vsum = (float*)((char*)d_ws + vsum_bytes);
        hipMemsetAsync(sbuf, 0, vsum_bytes, stream);
        sweep_kernel<0, true><<<gs, bs, 0, stream>>>(x, W, vsum, sbuf);
        squash_kernel<0, true><<<gq, bq, 0, stream>>>(sbuf, vsum, out);
        sweep_kernel<1, true><<<gs, bs, 0, stream>>>(x, W, vsum, sbuf);
        squash_kernel<1, true><<<gq, bq, 0, stream>>>(sbuf, vsum, out);
        sweep_kernel<2, true><<<gs, bs, 0, stream>>>(x, W, vsum, sbuf);
        squash_kernel<2, true><<<gq, bq, 0, stream>>>(sbuf, vsum, out);
    }
}